// Round 2
// baseline (801.590 us; speedup 1.0000x reference)
//
#include <hip/hip_runtime.h>
#include <hip/hip_bf16.h>

// Problem constants (fixed by the reference file)
#define NNODES 50000
#define NEDGES 1600000
#define CE 64
#define CN 256
#define COUT 256
#define KTOT (CE + CN)   // 320
#define BCAP 64          // bucket capacity per node (Poisson(32); overflow -> atomic fallback)

// Fused-kernel tile
#define FBM 128          // node rows per block
#define FBN 256          // output cols per block (= COUT, so gather runs once)
#define FBK 32           // K-step
#define PAD 8            // LDS row pad (bf16): frag ds_read_b128 at 2-way aliasing (free)

typedef __attribute__((ext_vector_type(8))) short bf16x8;
typedef __attribute__((ext_vector_type(4))) float f32x4;

__device__ inline ushort f2bf(float f) {
    __hip_bfloat16 h = __float2bfloat16(f);
    return *(ushort*)&h;
}

// ---------------------------------------------------------------------------
// Kernel 1: bucket fill. One thread per edge. pos = atomicAdd(count[r]) gives
// both degree and slot. Overflow edges (rare: P(deg>64) ~ 1e-8/node) fall back
// to fp32 atomics into zeroed Aovf, keeping correctness unconditional.
// ---------------------------------------------------------------------------
__global__ __launch_bounds__(256) void fill_kernel(
    const int* __restrict__ row_idx,
    const float* __restrict__ ea,
    int* __restrict__ counts,
    int* __restrict__ buckets,
    float* __restrict__ Aovf)
{
    int e = blockIdx.x * 256 + threadIdx.x;   // exactly NEDGES threads
    int r = row_idx[e];
    int pos = atomicAdd(&counts[r], 1);
    if (pos < BCAP) {
        buckets[r * BCAP + pos] = e;
    } else {
        for (int c = 0; c < CE; ++c)
            atomicAdd(&Aovf[r * CE + c], ea[e * CE + c]);
    }
}

// ---------------------------------------------------------------------------
// Kernel 2: prep. Transpose [W_pass; W_self] (320x256 fp32) into bf16
// Wt[n][k] (n-major, k contiguous) and fuse biases. 320 blocks x 256 thr.
// ---------------------------------------------------------------------------
__global__ __launch_bounds__(256) void prep_kernel(
    const float* __restrict__ Wp, const float* __restrict__ Ws,
    const float* __restrict__ bp, const float* __restrict__ bs,
    ushort* __restrict__ Wt, float* __restrict__ bias)
{
    int k = blockIdx.x;          // 0..319
    int n = threadIdx.x;         // 0..255
    float v = (k < CE) ? Wp[k * COUT + n] : Ws[(k - CE) * COUT + n];
    Wt[n * KTOT + k] = f2bf(v);
    if (k == 0) bias[n] = bp[n] + bs[n];
}

// ---------------------------------------------------------------------------
// Kernel 3: FUSED gather + MFMA GEMM.
//   Phase 0: each wave gathers 32 nodes' edge sums (coalesced 256B bucket
//            load + __shfl edge-id broadcast, 8 edges in flight), normalizes
//            by 1/D, writes bf16 rows straight into the LDS A-tile.
//   Phase 1: out = relu([Ag | bf16(X)] @ Wt^T + bias), 128x256 tile, BK=32,
//            4 waves each computing a 64x128 quadrant (4x8 frags of
//            mfma_f32_16x16x32_bf16). K-steps 0-1 read the gathered tile
//            (no staging); steps 2-9 stage X (read exactly once per node).
//
//   EXEC-MASK DISCIPLINE (round-1 bug fix): every __shfl executes with all 64
//   lanes active; per-lane predicates only guard the dependent memory access.
//   ds_bpermute from an exec-masked source lane is undefined on CDNA.
// ---------------------------------------------------------------------------
__global__ __launch_bounds__(256, 2) void fused_kernel(
    const float4* __restrict__ ea4,    // edge_attr as (E*16) float4
    const int* __restrict__ counts,
    const int* __restrict__ buckets,
    const float* __restrict__ D,
    const float4* __restrict__ Aovf4,  // overflow sums (read only if deg>BCAP)
    const float* __restrict__ X,       // NNODES x CN fp32
    const ushort* __restrict__ Wt,     // COUT x KTOT bf16 (n-major)
    const float* __restrict__ bias,    // COUT fp32 (bp+bs)
    float* __restrict__ out)           // NNODES x COUT
{
    __shared__ ushort sAg0[FBM][FBK + PAD];  // gathered A, k 0..31
    __shared__ ushort sAg1[FBM][FBK + PAD];  // gathered A, k 32..63
    __shared__ ushort sX [FBM][FBK + PAD];   // X-part staging
    __shared__ ushort sB [FBN][FBK + PAD];   // Wt staging

    const int tid  = threadIdx.x;
    const int wave = tid >> 6;
    const int lane = tid & 63;
    const int row0 = blockIdx.x * FBM;

    // ---------------- phase 0: gather 32 nodes per wave ----------------
    {
        const int sub = lane >> 4;           // 4 edges / iteration
        const int c4  = lane & 15;           // float4 channel slot

        // prefetch counts + D for this wave's 32 nodes (one vector load each)
        const int nb  = row0 + wave * 32 + (lane & 31);
        const int nbc = (nb < NNODES) ? nb : (NNODES - 1);
        const int   cntv = counts[nbc];
        const float dvv  = D[nbc];

        for (int lm = 0; lm < 32; ++lm) {
            const int m = wave * 32 + lm;
            const int n = row0 + m;                  // wave-uniform
            // shfl with all lanes active; predicate applied after
            const int cshf = __shfl(cntv, lm);
            const int rawdeg = (n < NNODES) ? cshf : 0;
            const int deg = (rawdeg < BCAP) ? rawdeg : BCAP;

            float4 a0 = make_float4(0.f, 0.f, 0.f, 0.f);
            float4 a1 = make_float4(0.f, 0.f, 0.f, 0.f);
            int bktv = 0;
            if (n < NNODES) bktv = buckets[(size_t)n * BCAP + lane];  // 256B coalesced, uniform branch

            int i = 0;
            for (; i + 8 <= deg; i += 8) {                 // uniform bound: all lanes active
                const int e0 = __shfl(bktv, i + sub);
                const int e1 = __shfl(bktv, i + 4 + sub);
                const float4 v0 = ea4[(size_t)e0 * 16 + c4];
                const float4 v1 = ea4[(size_t)e1 * 16 + c4];
                a0.x += v0.x; a0.y += v0.y; a0.z += v0.z; a0.w += v0.w;
                a1.x += v1.x; a1.y += v1.y; a1.z += v1.z; a1.w += v1.w;
            }
            for (; i < deg; i += 4) {                      // uniform bound: all lanes active
                const int e0 = __shfl(bktv, i + sub);      // slot may be >= deg: garbage but defined
                if (i + sub < deg) {                       // mask the dependent load only
                    const float4 v0 = ea4[(size_t)e0 * 16 + c4];
                    a0.x += v0.x; a0.y += v0.y; a0.z += v0.z; a0.w += v0.w;
                }
            }

            a0.x += a1.x; a0.y += a1.y; a0.z += a1.z; a0.w += a1.w;
            a0.x += __shfl_xor(a0.x, 16); a0.x += __shfl_xor(a0.x, 32);
            a0.y += __shfl_xor(a0.y, 16); a0.y += __shfl_xor(a0.y, 32);
            a0.z += __shfl_xor(a0.z, 16); a0.z += __shfl_xor(a0.z, 32);
            a0.w += __shfl_xor(a0.w, 16); a0.w += __shfl_xor(a0.w, 32);

            const float dv = __shfl(dvv, lm);              // hoisted: all lanes active
            if (sub == 0) {
                const float invd = (n < NNODES) ? (1.0f / dv) : 0.f;
                float4 prev = make_float4(0.f, 0.f, 0.f, 0.f);
                if (n < NNODES && rawdeg > BCAP)
                    prev = Aovf4[(size_t)n * 16 + c4];
                ushort4 o;
                o.x = f2bf((a0.x + prev.x) * invd);
                o.y = f2bf((a0.y + prev.y) * invd);
                o.z = f2bf((a0.z + prev.z) * invd);
                o.w = f2bf((a0.w + prev.w) * invd);
                ushort* dst = (c4 < 8) ? &sAg0[m][c4 * 4] : &sAg1[m][(c4 - 8) * 4];
                *(ushort4*)dst = o;
            }
        }
    }
    // sAg* reads are ordered by the first K-step's __syncthreads below.

    // ---------------- phase 1: GEMM ----------------
    const int m16 = lane & 15;
    const int kg  = lane >> 4;
    const int wr  = (wave >> 1) * 64;        // wave row offset (0/64)
    const int wc  = (wave & 1) * 128;        // wave col offset (0/128)
    const int sr  = tid >> 1;                // X staging row
    const int sh  = tid & 1;                 // X staging k-half
    const int brr = tid >> 2;                // B staging row base
    const int bq  = tid & 3;                 // B staging 16B quarter

    f32x4 acc[4][8];
    #pragma unroll
    for (int i = 0; i < 4; ++i)
        #pragma unroll
        for (int j = 0; j < 8; ++j)
            acc[i][j] = (f32x4){0.f, 0.f, 0.f, 0.f};

    #pragma unroll
    for (int ks = 0; ks < KTOT / FBK; ++ks) {    // 10 steps
        const int k0 = ks * FBK;

        // --- stage B-tile: 256 cols x 32 k from Wt (bf16, k contiguous) ---
        #pragma unroll
        for (int p = 0; p < 4; ++p) {
            const int r = brr + p * 64;
            const uint4 v = *(const uint4*)(Wt + (size_t)r * KTOT + k0 + bq * 8);
            *(uint4*)&sB[r][bq * 8] = v;
        }

        // --- stage A-tile from X (fp32 -> bf16) for k >= CE ---
        if (ks >= 2) {
            const int gn = row0 + sr;
            uint4 v0 = {0, 0, 0, 0}, v1 = {0, 0, 0, 0};
            if (gn < NNODES) {
                const float4* xs = (const float4*)(X + (size_t)gn * CN + (k0 - CE) + sh * 16);
                const float4 a = xs[0], b = xs[1], c = xs[2], d = xs[3];
                union { ushort us[8]; uint4 u; } p0, p1;
                p0.us[0]=f2bf(a.x); p0.us[1]=f2bf(a.y); p0.us[2]=f2bf(a.z); p0.us[3]=f2bf(a.w);
                p0.us[4]=f2bf(b.x); p0.us[5]=f2bf(b.y); p0.us[6]=f2bf(b.z); p0.us[7]=f2bf(b.w);
                p1.us[0]=f2bf(c.x); p1.us[1]=f2bf(c.y); p1.us[2]=f2bf(c.z); p1.us[3]=f2bf(c.w);
                p1.us[4]=f2bf(d.x); p1.us[5]=f2bf(d.y); p1.us[6]=f2bf(d.z); p1.us[7]=f2bf(d.w);
                v0 = p0.u; v1 = p1.u;
            }
            *(uint4*)&sX[sr][sh * 16]     = v0;
            *(uint4*)&sX[sr][sh * 16 + 8] = v1;
        }
        __syncthreads();

        const ushort (*sa)[FBK + PAD] = (ks == 0) ? sAg0 : (ks == 1) ? sAg1 : sX;
        bf16x8 aF[4];
        #pragma unroll
        for (int i = 0; i < 4; ++i)
            aF[i] = *(const bf16x8*)&sa[wr + i * 16 + m16][kg * 8];
        #pragma unroll
        for (int j = 0; j < 8; ++j) {
            const bf16x8 bFj = *(const bf16x8*)&sB[wc + j * 16 + m16][kg * 8];
            #pragma unroll
            for (int i = 0; i < 4; ++i)
                acc[i][j] = __builtin_amdgcn_mfma_f32_16x16x32_bf16(aF[i], bFj, acc[i][j], 0, 0, 0);
        }
        __syncthreads();
    }

    // --- epilogue: D layout col=lane&15, row=quad*4+reg ---
    #pragma unroll
    for (int j = 0; j < 8; ++j) {
        const int col = wc + j * 16 + m16;
        const float bv = bias[col];
        #pragma unroll
        for (int i = 0; i < 4; ++i) {
            const int rbase = row0 + wr + i * 16 + kg * 4;
            #pragma unroll
            for (int t = 0; t < 4; ++t) {
                const int row = rbase + t;
                if (row < NNODES)
                    out[(size_t)row * COUT + col] = fmaxf(acc[i][j][t] + bv, 0.f);
            }
        }
    }
}

extern "C" void kernel_launch(void* const* d_in, const int* in_sizes, int n_in,
                              void* d_out, int out_size, void* d_ws, size_t ws_size,
                              hipStream_t stream) {
    const float* D         = (const float*)d_in[0];
    const int*   row_idx   = (const int*)  d_in[1];
    const float* edge_attr = (const float*)d_in[2];
    const float* X         = (const float*)d_in[3];
    const float* W_pass    = (const float*)d_in[4];
    const float* b_pass    = (const float*)d_in[5];
    const float* W_self    = (const float*)d_in[6];
    const float* b_self    = (const float*)d_in[7];
    float* out = (float*)d_out;

    // workspace layout (~26 MB of the ~1.6 GB ws)
    char* ws = (char*)d_ws;
    size_t off = 0;
    float* Aovf   = (float*)(ws + off); off += (size_t)NNODES * CE * 4;        // 12.8 MB
    int*   counts = (int*)  (ws + off); off += (size_t)NNODES * 4;             // 0.2 MB
    int*   buckets= (int*)  (ws + off); off += (size_t)NNODES * BCAP * 4;      // 12.8 MB
    ushort* Wt    = (ushort*)(ws + off); off += (size_t)COUT * KTOT * 2;       // 160 KB
    float* bias   = (float*)(ws + off); off += (size_t)COUT * 4;

    hipMemsetAsync(Aovf, 0, (size_t)NNODES * CE * sizeof(float), stream);
    hipMemsetAsync(counts, 0, (size_t)NNODES * sizeof(int), stream);

    fill_kernel<<<dim3(NEDGES / 256), dim3(256), 0, stream>>>(
        row_idx, edge_attr, counts, buckets, Aovf);

    prep_kernel<<<dim3(KTOT), dim3(256), 0, stream>>>(
        W_pass, W_self, b_pass, b_self, Wt, bias);

    fused_kernel<<<dim3((NNODES + FBM - 1) / FBM), dim3(256), 0, stream>>>(
        (const float4*)edge_attr, counts, buckets, D, (const float4*)Aovf,
        X, Wt, bias, out);
}

// Round 3
// 775.774 us; speedup vs baseline: 1.0333x; 1.0333x over previous
//
#include <hip/hip_runtime.h>
#include <hip/hip_bf16.h>

// Problem constants (fixed by the reference file)
#define NNODES 50000
#define NEDGES 1600000
#define CE 64
#define CN 256
#define COUT 256
#define KTOT (CE + CN)   // 320
#define BCAP 64          // bucket capacity per node (Poisson(32); overflow -> atomic fallback)

// GEMM tile
#define GBM 128          // node rows per block
#define GBN 256          // output cols per block (= COUT: X read exactly once)
#define GBK 32           // K-step
#define PAD 8            // LDS row pad (bf16): frag ds_read_b128 at 2-way aliasing (free)

typedef __attribute__((ext_vector_type(8))) short bf16x8;
typedef __attribute__((ext_vector_type(4))) float f32x4;

__device__ inline ushort f2bf(float f) {
    __hip_bfloat16 h = __float2bfloat16(f);
    return *(ushort*)&h;
}

// ---------------------------------------------------------------------------
// Kernel 1: bucket fill. One thread per edge. pos = atomicAdd(count[r]) gives
// both degree and slot. Overflow edges (rare: P(deg>64) ~ 1e-8/node) fall back
// to fp32 atomics into zeroed Aovf, keeping correctness unconditional.
// ---------------------------------------------------------------------------
__global__ __launch_bounds__(256) void fill_kernel(
    const int* __restrict__ row_idx,
    const float* __restrict__ ea,
    int* __restrict__ counts,
    int* __restrict__ buckets,
    float* __restrict__ Aovf)
{
    int e = blockIdx.x * 256 + threadIdx.x;   // exactly NEDGES threads
    int r = row_idx[e];
    int pos = atomicAdd(&counts[r], 1);
    if (pos < BCAP) {
        buckets[r * BCAP + pos] = e;
    } else {
        for (int c = 0; c < CE; ++c)
            atomicAdd(&Aovf[r * CE + c], ea[e * CE + c]);
    }
}

// ---------------------------------------------------------------------------
// Kernel 2: prep. Transpose [W_pass; W_self] (320x256 fp32) into bf16
// Wt[n][k] (n-major, k contiguous) and fuse biases. 320 blocks x 256 thr.
// ---------------------------------------------------------------------------
__global__ __launch_bounds__(256) void prep_kernel(
    const float* __restrict__ Wp, const float* __restrict__ Ws,
    const float* __restrict__ bp, const float* __restrict__ bs,
    ushort* __restrict__ Wt, float* __restrict__ bias)
{
    int k = blockIdx.x;          // 0..319
    int n = threadIdx.x;         // 0..255
    float v = (k < CE) ? Wp[k * COUT + n] : Ws[(k - CE) * COUT + n];
    Wt[n * KTOT + k] = f2bf(v);
    if (k == 0) bias[n] = bp[n] + bs[n];
}

// ---------------------------------------------------------------------------
// Kernel 3: gather. One wave per node (50000 waves: full TLP for latency
// hiding). The whole 64-entry bucket is loaded ONCE into a register
// (256B coalesced), edge ids broadcast via __shfl -- no per-round bucket
// pointer-chase. 16 edges in flight (4 accumulators). Aovf read only on
// the (rare) overflow path. Emits normalized bf16 A rows.
// EXEC-MASK DISCIPLINE: every __shfl runs with all 64 lanes active.
// ---------------------------------------------------------------------------
__global__ __launch_bounds__(256) void gather_kernel(
    const float4* __restrict__ ea4,    // edge_attr as (E*16) float4
    const int* __restrict__ counts,
    const int* __restrict__ buckets,
    const float* __restrict__ D,
    const float4* __restrict__ Aovf4,  // overflow sums (read only if deg>BCAP)
    ushort* __restrict__ Abf)          // out: NNODES x CE bf16, normalized
{
    const int wave = threadIdx.x >> 6;
    const int lane = threadIdx.x & 63;
    const int n = blockIdx.x * 4 + wave;      // 12500 * 4 == NNODES exactly
    const int sub = lane >> 4;
    const int c4  = lane & 15;

    const int rawdeg = counts[n];             // uniform address: broadcast
    const int deg = (rawdeg < BCAP) ? rawdeg : BCAP;
    const int bktv = buckets[(size_t)n * BCAP + lane];   // 256B coalesced, once

    float4 a0 = make_float4(0.f,0.f,0.f,0.f);
    float4 a1 = make_float4(0.f,0.f,0.f,0.f);
    float4 a2 = make_float4(0.f,0.f,0.f,0.f);
    float4 a3 = make_float4(0.f,0.f,0.f,0.f);

    int i = 0;
    for (; i + 16 <= deg; i += 16) {          // 16 edges / 4 loads in flight
        const int e0 = __shfl(bktv, i + sub);
        const int e1 = __shfl(bktv, i + 4  + sub);
        const int e2 = __shfl(bktv, i + 8  + sub);
        const int e3 = __shfl(bktv, i + 12 + sub);
        const float4 v0 = ea4[(size_t)e0 * 16 + c4];
        const float4 v1 = ea4[(size_t)e1 * 16 + c4];
        const float4 v2 = ea4[(size_t)e2 * 16 + c4];
        const float4 v3 = ea4[(size_t)e3 * 16 + c4];
        a0.x += v0.x; a0.y += v0.y; a0.z += v0.z; a0.w += v0.w;
        a1.x += v1.x; a1.y += v1.y; a1.z += v1.z; a1.w += v1.w;
        a2.x += v2.x; a2.y += v2.y; a2.z += v2.z; a2.w += v2.w;
        a3.x += v3.x; a3.y += v3.y; a3.z += v3.z; a3.w += v3.w;
    }
    for (; i + 4 <= deg; i += 4) {
        const int e0 = __shfl(bktv, i + sub);
        const float4 v0 = ea4[(size_t)e0 * 16 + c4];
        a0.x += v0.x; a0.y += v0.y; a0.z += v0.z; a0.w += v0.w;
    }
    if (i < deg) {                            // wave-uniform branch
        const int e0 = __shfl(bktv, i + sub); // all lanes active for the shfl
        if (i + sub < deg) {                  // mask only the dependent load
            const float4 v0 = ea4[(size_t)e0 * 16 + c4];
            a0.x += v0.x; a0.y += v0.y; a0.z += v0.z; a0.w += v0.w;
        }
    }

    a0.x += a1.x + a2.x + a3.x;
    a0.y += a1.y + a2.y + a3.y;
    a0.z += a1.z + a2.z + a3.z;
    a0.w += a1.w + a2.w + a3.w;
    a0.x += __shfl_xor(a0.x, 16); a0.x += __shfl_xor(a0.x, 32);
    a0.y += __shfl_xor(a0.y, 16); a0.y += __shfl_xor(a0.y, 32);
    a0.z += __shfl_xor(a0.z, 16); a0.z += __shfl_xor(a0.z, 32);
    a0.w += __shfl_xor(a0.w, 16); a0.w += __shfl_xor(a0.w, 32);

    if (sub == 0) {
        const float invd = 1.0f / D[n];
        float4 prev = make_float4(0.f,0.f,0.f,0.f);
        if (rawdeg > BCAP)                    // rare overflow path only
            prev = Aovf4[(size_t)n * 16 + c4];
        ushort4 o;
        o.x = f2bf((a0.x + prev.x) * invd);
        o.y = f2bf((a0.y + prev.y) * invd);
        o.z = f2bf((a0.z + prev.z) * invd);
        o.w = f2bf((a0.w + prev.w) * invd);
        *(ushort4*)&Abf[(size_t)n * CE + c4 * 4] = o;   // 8B aligned
    }
}

// ---------------------------------------------------------------------------
// Kernel 4: MFMA bf16 GEMM. out = relu([Abf | bf16(X)] @ Wt^T + bias)
// 128x256 tile (grid.y == 1: X is read exactly once), BK=32, 256 threads
// (4 waves, each a 64x128 quadrant = 4x8 frags of mfma_f32_16x16x32_bf16).
// K-steps 0-1 stage Abf (bf16 passthrough); steps 2-9 stage X (fp32->bf16).
// ---------------------------------------------------------------------------
__global__ __launch_bounds__(256, 2) void mfma_gemm_kernel(
    const ushort* __restrict__ Abf,   // NNODES x CE bf16 (normalized)
    const float* __restrict__ X,      // NNODES x CN fp32
    const ushort* __restrict__ Wt,    // COUT x KTOT bf16 (n-major)
    const float* __restrict__ bias,   // COUT fp32 (bp+bs)
    float* __restrict__ out)          // NNODES x COUT
{
    __shared__ ushort sA[GBM][GBK + PAD];   // [m][k], k contiguous
    __shared__ ushort sB[GBN][GBK + PAD];   // [n][k], k contiguous

    const int tid  = threadIdx.x;
    const int wave = tid >> 6;
    const int lane = tid & 63;
    const int row0 = blockIdx.x * GBM;
    const int m16  = lane & 15;
    const int kg   = lane >> 4;              // k-quad 0..3
    const int wr   = (wave >> 1) * 64;       // wave row offset (0/64)
    const int wc   = (wave & 1) * 128;       // wave col offset (0/128)
    const int sr   = tid >> 1;               // A staging row 0..127
    const int sh   = tid & 1;                // A staging k-half (16 elems)
    const int brr  = tid >> 2;               // B staging row base 0..63
    const int bq   = tid & 3;                // B staging 16B quarter

    f32x4 acc[4][8];
    #pragma unroll
    for (int i = 0; i < 4; ++i)
        #pragma unroll
        for (int j = 0; j < 8; ++j)
            acc[i][j] = (f32x4){0.f, 0.f, 0.f, 0.f};

    #pragma unroll
    for (int ks = 0; ks < KTOT / GBK; ++ks) {    // 10 steps
        const int k0 = ks * GBK;

        // --- stage B-tile: 256 cols x 32 k from Wt (bf16, k contiguous) ---
        #pragma unroll
        for (int p = 0; p < 4; ++p) {
            const int r = brr + p * 64;
            const uint4 v = *(const uint4*)(Wt + (size_t)r * KTOT + k0 + bq * 8);
            *(uint4*)&sB[r][bq * 8] = v;
        }

        // --- stage A-tile: Abf passthrough (ks<2) or X fp32->bf16 (ks>=2) ---
        {
            const int gn = row0 + sr;
            uint4 v0 = {0,0,0,0}, v1 = {0,0,0,0};
            if (gn < NNODES) {
                if (ks < 2) {
                    const uint4* src = (const uint4*)(Abf + (size_t)gn * CE + k0 + sh * 16);
                    v0 = src[0]; v1 = src[1];
                } else {
                    const float4* xs = (const float4*)(X + (size_t)gn * CN + (k0 - CE) + sh * 16);
                    const float4 a = xs[0], b = xs[1], c = xs[2], d = xs[3];
                    union { ushort us[8]; uint4 u; } p0, p1;
                    p0.us[0]=f2bf(a.x); p0.us[1]=f2bf(a.y); p0.us[2]=f2bf(a.z); p0.us[3]=f2bf(a.w);
                    p0.us[4]=f2bf(b.x); p0.us[5]=f2bf(b.y); p0.us[6]=f2bf(b.z); p0.us[7]=f2bf(b.w);
                    p1.us[0]=f2bf(c.x); p1.us[1]=f2bf(c.y); p1.us[2]=f2bf(c.z); p1.us[3]=f2bf(c.w);
                    p1.us[4]=f2bf(d.x); p1.us[5]=f2bf(d.y); p1.us[6]=f2bf(d.z); p1.us[7]=f2bf(d.w);
                    v0 = p0.u; v1 = p1.u;
                }
            }
            *(uint4*)&sA[sr][sh * 16]     = v0;
            *(uint4*)&sA[sr][sh * 16 + 8] = v1;
        }
        __syncthreads();

        bf16x8 aF[4];
        #pragma unroll
        for (int i = 0; i < 4; ++i)
            aF[i] = *(const bf16x8*)&sA[wr + i * 16 + m16][kg * 8];
        #pragma unroll
        for (int j = 0; j < 8; ++j) {
            const bf16x8 bFj = *(const bf16x8*)&sB[wc + j * 16 + m16][kg * 8];
            #pragma unroll
            for (int i = 0; i < 4; ++i)
                acc[i][j] = __builtin_amdgcn_mfma_f32_16x16x32_bf16(aF[i], bFj, acc[i][j], 0, 0, 0);
        }
        __syncthreads();
    }

    // --- epilogue: D layout col=lane&15, row=quad*4+reg ---
    #pragma unroll
    for (int j = 0; j < 8; ++j) {
        const int col = wc + j * 16 + m16;
        const float bv = bias[col];
        #pragma unroll
        for (int i = 0; i < 4; ++i) {
            const int rbase = row0 + wr + i * 16 + kg * 4;
            #pragma unroll
            for (int t = 0; t < 4; ++t) {
                const int row = rbase + t;
                if (row < NNODES)
                    out[(size_t)row * COUT + col] = fmaxf(acc[i][j][t] + bv, 0.f);
            }
        }
    }
}

extern "C" void kernel_launch(void* const* d_in, const int* in_sizes, int n_in,
                              void* d_out, int out_size, void* d_ws, size_t ws_size,
                              hipStream_t stream) {
    const float* D         = (const float*)d_in[0];
    const int*   row_idx   = (const int*)  d_in[1];
    const float* edge_attr = (const float*)d_in[2];
    const float* X         = (const float*)d_in[3];
    const float* W_pass    = (const float*)d_in[4];
    const float* b_pass    = (const float*)d_in[5];
    const float* W_self    = (const float*)d_in[6];
    const float* b_self    = (const float*)d_in[7];
    float* out = (float*)d_out;

    // workspace layout (~32.4 MB of the ~1.6 GB ws)
    char* ws = (char*)d_ws;
    size_t off = 0;
    float* Aovf   = (float*)(ws + off); off += (size_t)NNODES * CE * 4;        // 12.8 MB
    int*   counts = (int*)  (ws + off); off += (size_t)NNODES * 4;             // 0.2 MB
    int*   buckets= (int*)  (ws + off); off += (size_t)NNODES * BCAP * 4;      // 12.8 MB
    ushort* Abf   = (ushort*)(ws + off); off += (size_t)NNODES * CE * 2;       // 6.4 MB
    ushort* Wt    = (ushort*)(ws + off); off += (size_t)COUT * KTOT * 2;       // 160 KB
    float* bias   = (float*)(ws + off); off += (size_t)COUT * 4;

    hipMemsetAsync(Aovf, 0, (size_t)NNODES * CE * sizeof(float), stream);
    hipMemsetAsync(counts, 0, (size_t)NNODES * sizeof(int), stream);

    fill_kernel<<<dim3(NEDGES / 256), dim3(256), 0, stream>>>(
        row_idx, edge_attr, counts, buckets, Aovf);

    prep_kernel<<<dim3(KTOT), dim3(256), 0, stream>>>(
        W_pass, W_self, b_pass, b_self, Wt, bias);

    gather_kernel<<<dim3(NNODES / 4), dim3(256), 0, stream>>>(
        (const float4*)edge_attr, counts, buckets, D, (const float4*)Aovf, Abf);

    mfma_gemm_kernel<<<dim3((NNODES + GBM - 1) / GBM), dim3(256), 0, stream>>>(
        Abf, X, Wt, bias, out);
}

// Round 5
// 734.491 us; speedup vs baseline: 1.0914x; 1.0562x over previous
//
#include <hip/hip_runtime.h>
#include <hip/hip_bf16.h>

// Problem constants (fixed by the reference file)
#define NNODES 50000
#define NEDGES 1600000
#define CE 64
#define CN 256
#define COUT 256
#define KTOT (CE + CN)   // 320
#define BCAP 64          // bucket capacity per node (Poisson(32); overflow -> atomic fallback)

// GEMM tile
#define GBM 128          // node rows per block
#define GBN 256          // output cols per block (= COUT: X read exactly once)
#define GBK 32           // K-step
#define PAD 8            // LDS row pad (bf16): frag ds_read_b128 at 2-way aliasing (free)

typedef __attribute__((ext_vector_type(8))) short bf16x8;
typedef __attribute__((ext_vector_type(4))) float f32x4;
// native vector types for __builtin_nontemporal_load (HIP float4/uint4 are
// classes and are rejected by the builtin)
typedef __attribute__((ext_vector_type(4))) float fvec4;
typedef __attribute__((ext_vector_type(4))) uint  uvec4;

__device__ inline ushort f2bf(float f) {
    __hip_bfloat16 h = __float2bfloat16(f);
    return *(ushort*)&h;
}

__device__ inline fvec4 ntload_f4(const float4* p) {
    return __builtin_nontemporal_load(reinterpret_cast<const fvec4*>(p));
}

// ---------------------------------------------------------------------------
// Kernel 1: prep (runs FIRST). Grid-stride zeroes counts + Aovf (replaces two
// hipMemsetAsync dispatches), transposes [W_pass; W_self] (320x256 fp32) into
// bf16 Wt[n][k] (n-major, k contiguous), fuses biases. 320 blocks x 256 thr.
// ---------------------------------------------------------------------------
__global__ __launch_bounds__(256) void prep_kernel(
    const float* __restrict__ Wp, const float* __restrict__ Ws,
    const float* __restrict__ bp, const float* __restrict__ bs,
    ushort* __restrict__ Wt, float* __restrict__ bias,
    int* __restrict__ counts, float4* __restrict__ Aovf4)
{
    const int k = blockIdx.x;          // 0..319
    const int n = threadIdx.x;         // 0..255
    const float v = (k < CE) ? Wp[k * COUT + n] : Ws[(k - CE) * COUT + n];
    Wt[n * KTOT + k] = f2bf(v);
    if (k == 0) bias[n] = bp[n] + bs[n];

    // folded zero-fill: counts (50000 ints) + Aovf (NNODES*CE/4 float4s)
    const int gid = k * 256 + n;                 // 0..81919
    const int gsz = KTOT * 256;                  // 81920
    if (gid < NNODES) counts[gid] = 0;
    const float4 z = make_float4(0.f, 0.f, 0.f, 0.f);
    for (int i = gid; i < NNODES * CE / 4; i += gsz)
        Aovf4[i] = z;
}

// ---------------------------------------------------------------------------
// Kernel 2: bucket fill. One thread per edge. pos = atomicAdd(count[r]) gives
// both degree and slot. Overflow edges (rare: P(deg>64) ~ 1e-8/node) fall back
// to fp32 atomics into zeroed Aovf, keeping correctness unconditional.
// ---------------------------------------------------------------------------
__global__ __launch_bounds__(256) void fill_kernel(
    const int* __restrict__ row_idx,
    const float* __restrict__ ea,
    int* __restrict__ counts,
    int* __restrict__ buckets,
    float* __restrict__ Aovf)
{
    int e = blockIdx.x * 256 + threadIdx.x;   // exactly NEDGES threads
    int r = row_idx[e];
    int pos = atomicAdd(&counts[r], 1);
    if (pos < BCAP) {
        buckets[r * BCAP + pos] = e;
    } else {
        for (int c = 0; c < CE; ++c)
            atomicAdd(&Aovf[r * CE + c], ea[e * CE + c]);
    }
}

// ---------------------------------------------------------------------------
// Kernel 3: gather. One wave per node (50000 waves: full TLP for latency
// hiding). The whole 64-entry bucket is loaded ONCE into a register
// (256B coalesced), edge ids broadcast via __shfl -- no per-round bucket
// pointer-chase. 16 edges in flight (4 accumulators). Aovf read only on
// the (rare) overflow path. Emits normalized bf16 A rows.
// EXEC-MASK DISCIPLINE: every __shfl runs with all 64 lanes active.
// Zero-reuse streams (ea4, buckets) use nontemporal loads to spare L2/L3.
// ---------------------------------------------------------------------------
__global__ __launch_bounds__(256) void gather_kernel(
    const float4* __restrict__ ea4,    // edge_attr as (E*16) float4
    const int* __restrict__ counts,
    const int* __restrict__ buckets,
    const float* __restrict__ D,
    const float4* __restrict__ Aovf4,  // overflow sums (read only if deg>BCAP)
    ushort* __restrict__ Abf)          // out: NNODES x CE bf16, normalized
{
    const int wave = threadIdx.x >> 6;
    const int lane = threadIdx.x & 63;
    const int n = blockIdx.x * 4 + wave;      // 12500 * 4 == NNODES exactly
    const int sub = lane >> 4;
    const int c4  = lane & 15;

    const int rawdeg = counts[n];             // uniform address: broadcast
    const int deg = (rawdeg < BCAP) ? rawdeg : BCAP;
    const int bktv = __builtin_nontemporal_load(&buckets[(size_t)n * BCAP + lane]);

    fvec4 a0 = (fvec4){0.f,0.f,0.f,0.f};
    fvec4 a1 = (fvec4){0.f,0.f,0.f,0.f};
    fvec4 a2 = (fvec4){0.f,0.f,0.f,0.f};
    fvec4 a3 = (fvec4){0.f,0.f,0.f,0.f};

    int i = 0;
    for (; i + 16 <= deg; i += 16) {          // 16 edges / 4 loads in flight
        const int e0 = __shfl(bktv, i + sub);
        const int e1 = __shfl(bktv, i + 4  + sub);
        const int e2 = __shfl(bktv, i + 8  + sub);
        const int e3 = __shfl(bktv, i + 12 + sub);
        const fvec4 v0 = ntload_f4(&ea4[(size_t)e0 * 16 + c4]);
        const fvec4 v1 = ntload_f4(&ea4[(size_t)e1 * 16 + c4]);
        const fvec4 v2 = ntload_f4(&ea4[(size_t)e2 * 16 + c4]);
        const fvec4 v3 = ntload_f4(&ea4[(size_t)e3 * 16 + c4]);
        a0 += v0; a1 += v1; a2 += v2; a3 += v3;
    }
    for (; i + 4 <= deg; i += 4) {
        const int e0 = __shfl(bktv, i + sub);
        a0 += ntload_f4(&ea4[(size_t)e0 * 16 + c4]);
    }
    if (i < deg) {                            // wave-uniform branch
        const int e0 = __shfl(bktv, i + sub); // all lanes active for the shfl
        if (i + sub < deg) {                  // mask only the dependent load
            a0 += ntload_f4(&ea4[(size_t)e0 * 16 + c4]);
        }
    }

    a0 += a1 + a2 + a3;
    a0.x += __shfl_xor(a0.x, 16); a0.x += __shfl_xor(a0.x, 32);
    a0.y += __shfl_xor(a0.y, 16); a0.y += __shfl_xor(a0.y, 32);
    a0.z += __shfl_xor(a0.z, 16); a0.z += __shfl_xor(a0.z, 32);
    a0.w += __shfl_xor(a0.w, 16); a0.w += __shfl_xor(a0.w, 32);

    if (sub == 0) {
        const float invd = 1.0f / D[n];
        float4 prev = make_float4(0.f,0.f,0.f,0.f);
        if (rawdeg > BCAP)                    // rare overflow path only
            prev = Aovf4[(size_t)n * 16 + c4];
        ushort4 o;
        o.x = f2bf((a0.x + prev.x) * invd);
        o.y = f2bf((a0.y + prev.y) * invd);
        o.z = f2bf((a0.z + prev.z) * invd);
        o.w = f2bf((a0.w + prev.w) * invd);
        *(ushort4*)&Abf[(size_t)n * CE + c4 * 4] = o;   // 8B aligned
    }
}

// ---------------------------------------------------------------------------
// Kernel 4: MFMA bf16 GEMM. out = relu([Abf | bf16(X)] @ Wt^T + bias)
// 128x256 tile (grid.y == 1: X is read exactly once), BK=32, 256 threads
// (4 waves, each a 64x128 quadrant = 4x8 frags of mfma_f32_16x16x32_bf16).
// K-steps 0-1 stage Abf (bf16 passthrough); steps 2-9 stage X (fp32->bf16).
// Abf/X are read-once streams -> nontemporal loads.
// ---------------------------------------------------------------------------
__global__ __launch_bounds__(256, 2) void mfma_gemm_kernel(
    const ushort* __restrict__ Abf,   // NNODES x CE bf16 (normalized)
    const float* __restrict__ X,      // NNODES x CN fp32
    const ushort* __restrict__ Wt,    // COUT x KTOT bf16 (n-major)
    const float* __restrict__ bias,   // COUT fp32 (bp+bs)
    float* __restrict__ out)          // NNODES x COUT
{
    __shared__ ushort sA[GBM][GBK + PAD];   // [m][k], k contiguous
    __shared__ ushort sB[GBN][GBK + PAD];   // [n][k], k contiguous

    const int tid  = threadIdx.x;
    const int wave = tid >> 6;
    const int lane = tid & 63;
    const int row0 = blockIdx.x * GBM;
    const int m16  = lane & 15;
    const int kg   = lane >> 4;              // k-quad 0..3
    const int wr   = (wave >> 1) * 64;       // wave row offset (0/64)
    const int wc   = (wave & 1) * 128;       // wave col offset (0/128)
    const int sr   = tid >> 1;               // A staging row 0..127
    const int sh   = tid & 1;                // A staging k-half (16 elems)
    const int brr  = tid >> 2;               // B staging row base 0..63
    const int bq   = tid & 3;                // B staging 16B quarter

    f32x4 acc[4][8];
    #pragma unroll
    for (int i = 0; i < 4; ++i)
        #pragma unroll
        for (int j = 0; j < 8; ++j)
            acc[i][j] = (f32x4){0.f, 0.f, 0.f, 0.f};

    #pragma unroll
    for (int ks = 0; ks < KTOT / GBK; ++ks) {    // 10 steps
        const int k0 = ks * GBK;

        // --- stage B-tile: 256 cols x 32 k from Wt (bf16, k contiguous) ---
        #pragma unroll
        for (int p = 0; p < 4; ++p) {
            const int r = brr + p * 64;
            const uvec4 v = *(const uvec4*)(Wt + (size_t)r * KTOT + k0 + bq * 8);
            *(uvec4*)&sB[r][bq * 8] = v;
        }

        // --- stage A-tile: Abf passthrough (ks<2) or X fp32->bf16 (ks>=2) ---
        {
            const int gn = row0 + sr;
            uvec4 v0 = (uvec4){0,0,0,0}, v1 = (uvec4){0,0,0,0};
            if (gn < NNODES) {
                if (ks < 2) {
                    const uvec4* src = (const uvec4*)(Abf + (size_t)gn * CE + k0 + sh * 16);
                    v0 = __builtin_nontemporal_load(&src[0]);
                    v1 = __builtin_nontemporal_load(&src[1]);
                } else {
                    const fvec4* xs = (const fvec4*)(X + (size_t)gn * CN + (k0 - CE) + sh * 16);
                    const fvec4 a = __builtin_nontemporal_load(&xs[0]);
                    const fvec4 b = __builtin_nontemporal_load(&xs[1]);
                    const fvec4 c = __builtin_nontemporal_load(&xs[2]);
                    const fvec4 d = __builtin_nontemporal_load(&xs[3]);
                    union { ushort us[8]; uvec4 u; } p0, p1;
                    p0.us[0]=f2bf(a.x); p0.us[1]=f2bf(a.y); p0.us[2]=f2bf(a.z); p0.us[3]=f2bf(a.w);
                    p0.us[4]=f2bf(b.x); p0.us[5]=f2bf(b.y); p0.us[6]=f2bf(b.z); p0.us[7]=f2bf(b.w);
                    p1.us[0]=f2bf(c.x); p1.us[1]=f2bf(c.y); p1.us[2]=f2bf(c.z); p1.us[3]=f2bf(c.w);
                    p1.us[4]=f2bf(d.x); p1.us[5]=f2bf(d.y); p1.us[6]=f2bf(d.z); p1.us[7]=f2bf(d.w);
                    v0 = p0.u; v1 = p1.u;
                }
            }
            *(uvec4*)&sA[sr][sh * 16]     = v0;
            *(uvec4*)&sA[sr][sh * 16 + 8] = v1;
        }
        __syncthreads();

        bf16x8 aF[4];
        #pragma unroll
        for (int i = 0; i < 4; ++i)
            aF[i] = *(const bf16x8*)&sA[wr + i * 16 + m16][kg * 8];
        #pragma unroll
        for (int j = 0; j < 8; ++j) {
            const bf16x8 bFj = *(const bf16x8*)&sB[wc + j * 16 + m16][kg * 8];
            #pragma unroll
            for (int i = 0; i < 4; ++i)
                acc[i][j] = __builtin_amdgcn_mfma_f32_16x16x32_bf16(aF[i], bFj, acc[i][j], 0, 0, 0);
        }
        __syncthreads();
    }

    // --- epilogue: D layout col=lane&15, row=quad*4+reg ---
    #pragma unroll
    for (int j = 0; j < 8; ++j) {
        const int col = wc + j * 16 + m16;
        const float bv = bias[col];
        #pragma unroll
        for (int i = 0; i < 4; ++i) {
            const int rbase = row0 + wr + i * 16 + kg * 4;
            #pragma unroll
            for (int t = 0; t < 4; ++t) {
                const int row = rbase + t;
                if (row < NNODES)
                    out[(size_t)row * COUT + col] = fmaxf(acc[i][j][t] + bv, 0.f);
            }
        }
    }
}

extern "C" void kernel_launch(void* const* d_in, const int* in_sizes, int n_in,
                              void* d_out, int out_size, void* d_ws, size_t ws_size,
                              hipStream_t stream) {
    const float* D         = (const float*)d_in[0];
    const int*   row_idx   = (const int*)  d_in[1];
    const float* edge_attr = (const float*)d_in[2];
    const float* X         = (const float*)d_in[3];
    const float* W_pass    = (const float*)d_in[4];
    const float* b_pass    = (const float*)d_in[5];
    const float* W_self    = (const float*)d_in[6];
    const float* b_self    = (const float*)d_in[7];
    float* out = (float*)d_out;

    // workspace layout (~32.4 MB of the ~1.6 GB ws)
    char* ws = (char*)d_ws;
    size_t off = 0;
    float* Aovf   = (float*)(ws + off); off += (size_t)NNODES * CE * 4;        // 12.8 MB
    int*   counts = (int*)  (ws + off); off += (size_t)NNODES * 4;             // 0.2 MB
    int*   buckets= (int*)  (ws + off); off += (size_t)NNODES * BCAP * 4;      // 12.8 MB
    ushort* Abf   = (ushort*)(ws + off); off += (size_t)NNODES * CE * 2;       // 6.4 MB
    ushort* Wt    = (ushort*)(ws + off); off += (size_t)COUT * KTOT * 2;       // 160 KB
    float* bias   = (float*)(ws + off); off += (size_t)COUT * 4;

    // prep first: zeroes counts/Aovf (replaces 2 memset dispatches) + Wt/bias
    prep_kernel<<<dim3(KTOT), dim3(256), 0, stream>>>(
        W_pass, W_self, b_pass, b_self, Wt, bias, counts, (float4*)Aovf);

    fill_kernel<<<dim3(NEDGES / 256), dim3(256), 0, stream>>>(
        row_idx, edge_attr, counts, buckets, Aovf);

    gather_kernel<<<dim3(NNODES / 4), dim3(256), 0, stream>>>(
        (const float4*)edge_attr, counts, buckets, D, (const float4*)Aovf, Abf);

    mfma_gemm_kernel<<<dim3((NNODES + GBM - 1) / GBM), dim3(256), 0, stream>>>(
        Abf, X, Wt, bias, out);
}